// Round 13
// baseline (1600.601 us; speedup 1.0000x reference)
//
#include <hip/hip_runtime.h>
#include <hip/hip_bf16.h>

typedef __hip_bfloat16 hipbf16;

#define H 128
#define NLAYERS 4
#define LN_EPS 1e-5f
#define ET 64           // node-kernel tile
#define EB 128          // edge-kernel tile (2 sub-groups of 32 per wave-half)

typedef __bf16 bf16x8 __attribute__((ext_vector_type(8)));
typedef unsigned short ushort8 __attribute__((ext_vector_type(8)));
typedef float floatx16 __attribute__((ext_vector_type(16)));

union frag_u { ushort8 u; bf16x8 b; };

__device__ __forceinline__ float silu(float x) {
    return x * __builtin_amdgcn_rcpf(1.f + __expf(-x));
}
__device__ __forceinline__ float b2f_bits(unsigned short u) { return __uint_as_float(((unsigned)u) << 16); }
__device__ __forceinline__ unsigned short f2b(float f) {
    unsigned u = __float_as_uint(f);
    unsigned r = ((u >> 16) & 1u) + 0x7fffu;
    return (unsigned short)((u + r) >> 16);
}

// ---------------- dtype detection (wire fp32 vs bf16) ----------------
__global__ void detect_kernel(const unsigned short* __restrict__ p, int nHalf,
                              int* __restrict__ flag) {
    int t = threadIdx.x;
    int bad = 0;
    for (int i = t; i < nHalf; i += 64) {
        unsigned short u = p[i];
        int e = (u >> 7) & 0xFF;
        if (e >= 0x8E) bad = 1;
    }
    unsigned long long m = __ballot(bad != 0);
    if (t == 0) *flag = (m != 0ULL) ? 1 : 0;   // 1 => fp32 wire
}

__global__ void conv_kernel(const void* __restrict__ src, float* __restrict__ dst,
                            int n, const int* __restrict__ flag) {
    int i = blockIdx.x * blockDim.x + threadIdx.x;
    if (i >= n) return;
    if (*flag) dst[i] = ((const float*)src)[i];
    else       dst[i] = b2f_bits(((const unsigned short*)src)[i]);
}

// Pack W[K x 128] (fp32) into MFMA B-fragment order
__global__ void pack_kernel(const float* __restrict__ W, unsigned short* __restrict__ blob,
                            int ksteps) {
    int idx = blockIdx.x * 256 + threadIdx.x;
    if (idx >= ksteps * 2048) return;
    int j  = idx & 7;
    int L  = (idx >> 3) & 63;
    int nt = (idx >> 9) & 3;
    int ks = idx >> 11;
    int k = ks * 16 + (L >> 5) * 8 + j;
    int n = nt * 32 + (L & 31);
    blob[idx] = f2b(W[k * H + n]);
}

__global__ void embed_kernel(const int* __restrict__ z, const float* __restrict__ emb,
                             float* __restrict__ h, unsigned short* __restrict__ hb, int n) {
    int idx = blockIdx.x * blockDim.x + threadIdx.x;
    if (idx >= n * H) return;
    int i = idx >> 7, j = idx & 127;
    float v = emb[z[i] * H + j];
    h[idx] = v;
    hb[idx] = f2b(v);
}

// ---------------- CSR build (counting sort by destination row) ----------------
__global__ void hist_kernel(const int* __restrict__ row, int* __restrict__ cnt, int nE) {
    int i = blockIdx.x * blockDim.x + threadIdx.x;
    if (i < nE) atomicAdd(&cnt[row[i]], 1);
}

__global__ __launch_bounds__(1024) void scan_kernel(const int* __restrict__ cnt,
                                                    int* __restrict__ rptr,
                                                    int* __restrict__ cur, int nN) {
    __shared__ int wsum[17];
    __shared__ int s_carry;
    int t = threadIdx.x;
    if (t == 0) s_carry = 0;
    __syncthreads();
    for (int base = 0; base < nN; base += 1024) {
        int i = base + t;
        int v = (i < nN) ? cnt[i] : 0;
        int x = v;
        #pragma unroll
        for (int off = 1; off < 64; off <<= 1) {
            int y = __shfl_up(x, off);
            if ((t & 63) >= off) x += y;
        }
        if ((t & 63) == 63) wsum[t >> 6] = x;
        __syncthreads();
        if (t == 0) {
            int s = 0;
            #pragma unroll
            for (int w = 0; w < 16; ++w) { int tmp = wsum[w]; wsum[w] = s; s += tmp; }
            wsum[16] = s;
        }
        __syncthreads();
        int cin = s_carry;
        int excl = cin + wsum[t >> 6] + (x - v);
        if (i < nN) { rptr[i] = excl; cur[i] = excl; }
        __syncthreads();
        if (t == 0) s_carry = cin + wsum[16];
        __syncthreads();
    }
    if (t == 0) rptr[nN] = s_carry;
}

__global__ void scatter_kernel(const int* __restrict__ row, const int* __restrict__ col,
                               const float* __restrict__ pos,
                               int* __restrict__ cur,
                               int* __restrict__ rowsS, int* __restrict__ colsS,
                               float* __restrict__ d2S, int nE) {
    int e = blockIdx.x * blockDim.x + threadIdx.x;
    if (e >= nE) return;
    int r = row[e], c = col[e];
    int p = atomicAdd(&cur[r], 1);
    rowsS[p] = r;
    colsS[p] = c;
    float dx = pos[r * 3 + 0] - pos[c * 3 + 0];
    float dy = pos[r * 3 + 1] - pos[c * 3 + 1];
    float dz = pos[r * 3 + 2] - pos[c * 3 + 2];
    d2S[p] = dx * dx + dy * dy + dz * dz;
}

// ---------------- edge MLP: 128-edge tile, direct-global A, 2x weight reuse --
// Each wave: M=64 (two 32-row sub-groups) x N=64. Every B-fragment load feeds
// 4 MFMA (vs 2 at ET=64) -> weight traffic per edge halves.
__global__ __launch_bounds__(256, 2) void edge_big(
    const unsigned short* __restrict__ hb,
    const int* __restrict__ rowsS, const int* __restrict__ colsS,
    const float* __restrict__ d2S,
    const unsigned short* __restrict__ pb1, const float* __restrict__ b1,
    const float* __restrict__ w1last,
    const unsigned short* __restrict__ pb2, const float* __restrict__ b2,
    float* __restrict__ agg, int nE)
{
    __shared__ __align__(16) unsigned short sT[EB * 136];   // 34816 B

    const int t = threadIdx.x;
    const int wv = t >> 6, lane = t & 63;
    const int wm = wv & 1, wn = wv >> 1;
    const int lm = lane & 31, lh = lane >> 5;
    const int n0 = wn * 64 + lm;
    const int p0 = blockIdx.x * EB;

    // per-sub edge ownership: lane lm owns edge p0 + wm*64 + s*32 + lm
    int ptag[2]; float dd[2];
    const unsigned short *rowp[2], *colp[2];
    #pragma unroll
    for (int s = 0; s < 2; ++s) {
        int p = p0 + wm * 64 + s * 32 + lm;
        bool valid = p < nE;
        int pc = valid ? p : (nE - 1);
        int nr = rowsS[pc], nc = colsS[pc];
        dd[s] = d2S[pc];
        ptag[s] = valid ? nr : -1;
        rowp[s] = hb + (size_t)nr * H + lh * 8;
        colp[s] = hb + (size_t)nc * H + lh * 8;
    }

    const float bias10 = b1[n0], bias11 = b1[n0 + 32];
    const float wl0 = w1last[n0], wl1 = w1last[n0 + 32];
    const float bias20 = b2[n0], bias21 = b2[n0 + 32];

    // GEMM1: [128,256] @ [256,128] (this wave: M 64 x N 64)
    floatx16 a00 = {}, a01 = {}, a10 = {}, a11 = {};
    #pragma unroll
    for (int ks = 0; ks < 16; ++ks) {
        frag_u fb0, fb1;
        fb0.u = *(const ushort8*)(pb1 + (size_t)((ks * 4 + wn * 2 + 0) * 64 + lane) * 8);
        fb1.u = *(const ushort8*)(pb1 + (size_t)((ks * 4 + wn * 2 + 1) * 64 + lane) * 8);
        frag_u x0, x1;
        x0.u = (ks < 8) ? *(const ushort8*)(rowp[0] + ks * 16)
                        : *(const ushort8*)(colp[0] + (ks - 8) * 16);
        x1.u = (ks < 8) ? *(const ushort8*)(rowp[1] + ks * 16)
                        : *(const ushort8*)(colp[1] + (ks - 8) * 16);
        a00 = __builtin_amdgcn_mfma_f32_32x32x16_bf16(x0.b, fb0.b, a00, 0, 0, 0);
        a01 = __builtin_amdgcn_mfma_f32_32x32x16_bf16(x0.b, fb1.b, a01, 0, 0, 0);
        a10 = __builtin_amdgcn_mfma_f32_32x32x16_bf16(x1.b, fb0.b, a10, 0, 0, 0);
        a11 = __builtin_amdgcn_mfma_f32_32x32x16_bf16(x1.b, fb1.b, a11, 0, 0, 0);
    }

    // epilogue 1: bias + d2*W1last (d2 via shfl), silu -> sT
    #pragma unroll
    for (int s = 0; s < 2; ++s) {
        const floatx16& u0 = s ? a10 : a00;
        const floatx16& u1 = s ? a11 : a01;
        #pragma unroll
        for (int r = 0; r < 16; ++r) {
            int mi = (r & 3) + 8 * (r >> 2) + 4 * lh;
            int m = wm * 64 + s * 32 + mi;
            float dm = __shfl(dd[s], mi);
            sT[m * 136 + n0]      = f2b(silu(u0[r] + bias10 + dm * wl0));
            sT[m * 136 + n0 + 32] = f2b(silu(u1[r] + bias11 + dm * wl1));
        }
    }
    __syncthreads();

    // GEMM2: [128,128] @ [128,128]
    floatx16 c00 = {}, c01 = {}, c10 = {}, c11 = {};
    const unsigned short* A20 = sT + (wm * 64 + lm) * 136 + lh * 8;
    const unsigned short* A21 = sT + (wm * 64 + 32 + lm) * 136 + lh * 8;
    #pragma unroll
    for (int ks = 0; ks < 8; ++ks) {
        frag_u fb0, fb1, x0, x1;
        fb0.u = *(const ushort8*)(pb2 + (size_t)((ks * 4 + wn * 2 + 0) * 64 + lane) * 8);
        fb1.u = *(const ushort8*)(pb2 + (size_t)((ks * 4 + wn * 2 + 1) * 64 + lane) * 8);
        x0.u = *(const ushort8*)(A20 + ks * 16);
        x1.u = *(const ushort8*)(A21 + ks * 16);
        c00 = __builtin_amdgcn_mfma_f32_32x32x16_bf16(x0.b, fb0.b, c00, 0, 0, 0);
        c01 = __builtin_amdgcn_mfma_f32_32x32x16_bf16(x0.b, fb1.b, c01, 0, 0, 0);
        c10 = __builtin_amdgcn_mfma_f32_32x32x16_bf16(x1.b, fb0.b, c10, 0, 0, 0);
        c11 = __builtin_amdgcn_mfma_f32_32x32x16_bf16(x1.b, fb1.b, c11, 0, 0, 0);
    }

    // epilogue 2: silu + register run-compaction per sub-group
    #pragma unroll
    for (int s = 0; s < 2; ++s) {
        const floatx16& u0 = s ? c10 : c00;
        const floatx16& u1 = s ? c11 : c01;
        #pragma unroll
        for (int g = 0; g < 4; ++g) {
            const int mi0 = 4 * lh + 8 * g;
            int prow = __shfl(ptag[s], mi0);
            float s0 = silu(u0[g * 4] + bias20);
            float s1 = silu(u1[g * 4] + bias21);
            #pragma unroll
            for (int k = 1; k < 4; ++k) {
                int rw = __shfl(ptag[s], mi0 + k);
                float v0 = silu(u0[g * 4 + k] + bias20);
                float v1 = silu(u1[g * 4 + k] + bias21);
                if (rw == prow) {
                    s0 += v0; s1 += v1;
                } else {
                    if (prow >= 0) {
                        atomicAdd(&agg[(size_t)prow * H + n0],      s0);
                        atomicAdd(&agg[(size_t)prow * H + n0 + 32], s1);
                    }
                    prow = rw; s0 = v0; s1 = v1;
                }
            }
            if (prow >= 0) {
                atomicAdd(&agg[(size_t)prow * H + n0],      s0);
                atomicAdd(&agg[(size_t)prow * H + n0 + 32], s1);
            }
        }
    }
}

// ---------------- node MLP via MFMA (round-9 proven form: block-staged) ------
__global__ __launch_bounds__(256) void node_mfma(
    const unsigned short* __restrict__ hb,
    const float* __restrict__ aggf,
    const unsigned short* __restrict__ pn1, const float* __restrict__ b1,
    const unsigned short* __restrict__ pn2, const float* __restrict__ b2,
    float* __restrict__ hnew, int nN)
{
    __shared__ __align__(16) unsigned short sA[ET * 264];

    const int t = threadIdx.x;
    const int i0 = blockIdx.x * ET;

    #pragma unroll
    for (int c = t; c < ET * 32; c += 256) {
        int e = c >> 5;
        int node = i0 + e; if (node >= nN) node = nN - 1;
        int f0 = (c & 31) * 8;
        ushort8 v;
        if (f0 < H) {
            v = *(const ushort8*)(hb + (size_t)node * H + f0);
        } else {
            const float* src = aggf + (size_t)node * H + (f0 - H);
            #pragma unroll
            for (int j = 0; j < 8; ++j) v[j] = f2b(src[j]);
        }
        *(ushort8*)(sA + e * 264 + (c & 31) * 8) = v;
    }
    __syncthreads();

    const int lane = t & 63;
    const int wv = t >> 6;
    const int wm = wv & 1, wn = wv >> 1;
    const int lm = lane & 31, lh = lane >> 5;
    const int n0 = wn * 64 + lm;

    floatx16 acc0 = {}, acc1 = {};
    const unsigned short* A0 = sA + (wm * 32 + lm) * 264 + lh * 8;
    #pragma unroll
    for (int ks = 0; ks < 16; ++ks) {
        frag_u a, fb0, fb1;
        a.u   = *(const ushort8*)(A0 + ks * 16);
        fb0.u = *(const ushort8*)(pn1 + (size_t)((ks * 4 + wn * 2 + 0) * 64 + lane) * 8);
        fb1.u = *(const ushort8*)(pn1 + (size_t)((ks * 4 + wn * 2 + 1) * 64 + lane) * 8);
        acc0 = __builtin_amdgcn_mfma_f32_32x32x16_bf16(a.b, fb0.b, acc0, 0, 0, 0);
        acc1 = __builtin_amdgcn_mfma_f32_32x32x16_bf16(a.b, fb1.b, acc1, 0, 0, 0);
    }
    __syncthreads();   // sA reads done before sT (aliased) written

    unsigned short* sT = sA;
    {
        float bias0 = b1[n0], bias1 = b1[n0 + 32];
        #pragma unroll
        for (int r = 0; r < 16; ++r) {
            int m = wm * 32 + (r & 3) + 8 * (r >> 2) + 4 * lh;
            sT[m * 136 + n0]      = f2b(silu(acc0[r] + bias0));
            sT[m * 136 + n0 + 32] = f2b(silu(acc1[r] + bias1));
        }
    }
    __syncthreads();

    floatx16 c0 = {}, c1 = {};
    const unsigned short* A2 = sT + (wm * 32 + lm) * 136 + lh * 8;
    #pragma unroll
    for (int ks = 0; ks < 8; ++ks) {
        frag_u a, fb0, fb1;
        a.u   = *(const ushort8*)(A2 + ks * 16);
        fb0.u = *(const ushort8*)(pn2 + (size_t)((ks * 4 + wn * 2 + 0) * 64 + lane) * 8);
        fb1.u = *(const ushort8*)(pn2 + (size_t)((ks * 4 + wn * 2 + 1) * 64 + lane) * 8);
        c0 = __builtin_amdgcn_mfma_f32_32x32x16_bf16(a.b, fb0.b, c0, 0, 0, 0);
        c1 = __builtin_amdgcn_mfma_f32_32x32x16_bf16(a.b, fb1.b, c1, 0, 0, 0);
    }
    {
        float bias0 = b2[n0], bias1 = b2[n0 + 32];
        #pragma unroll
        for (int r = 0; r < 16; ++r) {
            int m = wm * 32 + (r & 3) + 8 * (r >> 2) + 4 * lh;
            int node = i0 + m;
            if (node < nN) {
                float* dst = hnew + (size_t)node * H;
                dst[n0]      = c0[r] + bias0;
                dst[n0 + 32] = c1[r] + bias1;
            }
        }
    }
}

// residual + layernorm; writes fp32 h and bf16 mirror
__global__ __launch_bounds__(256) void ln_kernel(
    float* __restrict__ h, unsigned short* __restrict__ hb,
    const float* __restrict__ hnew,
    const float* __restrict__ G, const float* __restrict__ B, int nN)
{
    __shared__ float rs[4], rq[4];
    int t = threadIdx.x;
    int local = t >> 7, j = t & 127;
    int i = blockIdx.x * 2 + local;
    float v = 0.f;
    if (i < nN) v = h[(size_t)i * H + j] + hnew[(size_t)i * H + j];
    float s = v, q = v * v;
    #pragma unroll
    for (int off = 32; off > 0; off >>= 1) {
        s += __shfl_down(s, off);
        q += __shfl_down(q, off);
    }
    int w = t >> 6;
    if ((t & 63) == 0) { rs[w] = s; rq[w] = q; }
    __syncthreads();
    int w0 = local * 2;
    float S = rs[w0] + rs[w0 + 1], Q = rq[w0] + rq[w0 + 1];
    float mu = S * (1.f / H);
    float var = Q * (1.f / H) - mu * mu;
    float y = (v - mu) * rsqrtf(var + LN_EPS) * G[j] + B[j];
    if (i < nN) {
        h[(size_t)i * H + j] = y;
        hb[(size_t)i * H + j] = f2b(y);
    }
}

__global__ void cast_kernel(const float* __restrict__ h, void* __restrict__ out,
                            int n, const int* __restrict__ flag) {
    int idx = blockIdx.x * blockDim.x + threadIdx.x;
    if (idx >= n) return;
    if (*flag) ((float*)out)[idx] = h[idx];
    else       ((hipbf16*)out)[idx] = __float2bfloat16(h[idx]);
}

extern "C" void kernel_launch(void* const* d_in, const int* in_sizes, int n_in,
                              void* d_out, int out_size, void* d_ws, size_t ws_size,
                              hipStream_t stream)
{
    const int* z  = (const int*)d_in[0];
    const int* ei = (const int*)d_in[2];

    const int nN = in_sizes[0];
    const int nE = in_sizes[2] / 2;
    const int* row = ei;
    const int* col = ei + nE;

    // ---- workspace layout (~77 MB total, proven safe) ----
    float* ws   = (float*)d_ws;
    int*   flag = (int*)ws;
    float* h    = ws + 64;
    unsigned short* hb = (unsigned short*)(h + (size_t)nN * H);
    float* agg  = (float*)(hb + (size_t)nN * H);
    float* conv = agg + (size_t)nN * H;

    const int n_pos = in_sizes[1];
    const int n_emb = in_sizes[3];
    const int n_ew1 = in_sizes[4], n_eb1 = in_sizes[5];
    const int n_ew2 = in_sizes[6], n_eb2 = in_sizes[7];
    const int n_nw1 = in_sizes[8], n_nb1 = in_sizes[9];
    const int n_nw2 = in_sizes[10], n_nb2 = in_sizes[11];
    const int n_lng = in_sizes[12], n_lnb = in_sizes[13];

    float* pos = conv;
    float* emb = pos + n_pos;
    float* ew1 = emb + n_emb;
    float* eb1 = ew1 + n_ew1;
    float* ew2 = eb1 + n_eb1;
    float* eb2 = ew2 + n_ew2;
    float* nw1 = eb2 + n_eb2;
    float* nb1 = nw1 + n_nw1;
    float* nw2 = nb1 + n_nb1;
    float* nb2 = nw2 + n_nw2;
    float* lng = nb2 + n_nb2;
    float* lnb = lng + n_lng;
    float* conv_end = lnb + n_lnb;

    unsigned short* pb1 = (unsigned short*)conv_end;          // 4 x 32768
    unsigned short* pb2 = pb1 + 4 * 32768;                    // 4 x 16384
    unsigned short* pn1 = pb2 + 4 * 16384;                    // 4 x 32768
    unsigned short* pn2 = pn1 + 4 * 32768;                    // 4 x 16384

    int* cnt   = (int*)(pn2 + 4 * 16384);
    int* rptr  = cnt + nN;
    int* cur   = rptr + nN + 1;
    int* rowsS = cur + nN;
    int* colsS = rowsS + nE;
    float* d2S = (float*)(colsS + nE);

    detect_kernel<<<1, 64, 0, stream>>>((const unsigned short*)d_in[4], 4096, flag);

    struct { const void* src; float* dst; int n; } cv[12] = {
        {d_in[1],  pos, n_pos}, {d_in[3],  emb, n_emb},
        {d_in[4],  ew1, n_ew1}, {d_in[5],  eb1, n_eb1},
        {d_in[6],  ew2, n_ew2}, {d_in[7],  eb2, n_eb2},
        {d_in[8],  nw1, n_nw1}, {d_in[9],  nb1, n_nb1},
        {d_in[10], nw2, n_nw2}, {d_in[11], nb2, n_nb2},
        {d_in[12], lng, n_lng}, {d_in[13], lnb, n_lnb},
    };
    for (int i = 0; i < 12; ++i)
        conv_kernel<<<(cv[i].n + 255) / 256, 256, 0, stream>>>(cv[i].src, cv[i].dst, cv[i].n, flag);

    for (int l = 0; l < NLAYERS; ++l) {
        pack_kernel<<<128, 256, 0, stream>>>(ew1 + (size_t)l * 257 * H, pb1 + l * 32768, 16);
        pack_kernel<<<64,  256, 0, stream>>>(ew2 + (size_t)l * H * H,   pb2 + l * 16384, 8);
        pack_kernel<<<128, 256, 0, stream>>>(nw1 + (size_t)l * 2 * H * H, pn1 + l * 32768, 16);
        pack_kernel<<<64,  256, 0, stream>>>(nw2 + (size_t)l * H * H,   pn2 + l * 16384, 8);
    }

    // CSR-order edges (counting sort by destination row)
    hipMemsetAsync(cnt, 0, (size_t)nN * sizeof(int), stream);
    hist_kernel<<<(nE + 255) / 256, 256, 0, stream>>>(row, cnt, nE);
    scan_kernel<<<1, 1024, 0, stream>>>(cnt, rptr, cur, nN);
    scatter_kernel<<<(nE + 255) / 256, 256, 0, stream>>>(row, col, pos, cur, rowsS, colsS, d2S, nE);

    embed_kernel<<<(nN * H + 255) / 256, 256, 0, stream>>>(z, emb, h, hb, nN);

    const int nTilesE = (nE + EB - 1) / EB;
    const int nTilesN = (nN + ET - 1) / ET;
    for (int l = 0; l < NLAYERS; ++l) {
        hipMemsetAsync(agg, 0, (size_t)nN * H * sizeof(float), stream);
        edge_big<<<nTilesE, 256, 0, stream>>>(
            hb, rowsS, colsS, d2S,
            pb1 + l * 32768, eb1 + (size_t)l * H,
            ew1 + (size_t)l * 257 * H + 256 * H,
            pb2 + l * 16384, eb2 + (size_t)l * H,
            agg, nE);
        node_mfma<<<nTilesN, 256, 0, stream>>>(
            hb, agg,
            pn1 + l * 32768, nb1 + (size_t)l * H,
            pn2 + l * 16384, nb2 + (size_t)l * H,
            agg /* hnew, overwritten in place */, nN);
        ln_kernel<<<(nN + 1) / 2, 256, 0, stream>>>(
            h, hb, agg, lng + (size_t)l * H, lnb + (size_t)l * H, nN);
    }
    cast_kernel<<<(nN * H + 255) / 256, 256, 0, stream>>>(h, d_out, nN * H, flag);
}

// Round 14
// 1480.630 us; speedup vs baseline: 1.0810x; 1.0810x over previous
//
#include <hip/hip_runtime.h>
#include <hip/hip_bf16.h>

typedef __hip_bfloat16 hipbf16;

#define H 128
#define NLAYERS 4
#define LN_EPS 1e-5f
#define ET 64           // tile for edge/node kernels

typedef __bf16 bf16x8 __attribute__((ext_vector_type(8)));
typedef unsigned short ushort8 __attribute__((ext_vector_type(8)));
typedef float floatx16 __attribute__((ext_vector_type(16)));

union frag_u { ushort8 u; bf16x8 b; };

__device__ __forceinline__ float silu(float x) {
    return x * __builtin_amdgcn_rcpf(1.f + __expf(-x));
}
__device__ __forceinline__ float b2f_bits(unsigned short u) { return __uint_as_float(((unsigned)u) << 16); }
__device__ __forceinline__ unsigned short f2b(float f) {
    unsigned u = __float_as_uint(f);
    unsigned r = ((u >> 16) & 1u) + 0x7fffu;
    return (unsigned short)((u + r) >> 16);
}

// ---------------- dtype detection (wire fp32 vs bf16) ----------------
__global__ void detect_kernel(const unsigned short* __restrict__ p, int nHalf,
                              int* __restrict__ flag) {
    int t = threadIdx.x;
    int bad = 0;
    for (int i = t; i < nHalf; i += 64) {
        unsigned short u = p[i];
        int e = (u >> 7) & 0xFF;
        if (e >= 0x8E) bad = 1;
    }
    unsigned long long m = __ballot(bad != 0);
    if (t == 0) *flag = (m != 0ULL) ? 1 : 0;   // 1 => fp32 wire
}

__global__ void conv_kernel(const void* __restrict__ src, float* __restrict__ dst,
                            int n, const int* __restrict__ flag) {
    int i = blockIdx.x * blockDim.x + threadIdx.x;
    if (i >= n) return;
    if (*flag) dst[i] = ((const float*)src)[i];
    else       dst[i] = b2f_bits(((const unsigned short*)src)[i]);
}

// Pack W[K x 128] (fp32) into MFMA B-fragment order (K = ksteps*16)
__global__ void pack_kernel(const float* __restrict__ W, unsigned short* __restrict__ blob,
                            int ksteps) {
    int idx = blockIdx.x * 256 + threadIdx.x;
    if (idx >= ksteps * 2048) return;
    int j  = idx & 7;
    int L  = (idx >> 3) & 63;
    int nt = (idx >> 9) & 3;
    int ks = idx >> 11;
    int k = ks * 16 + (L >> 5) * 8 + j;
    int n = nt * 32 + (L & 31);
    blob[idx] = f2b(W[k * H + n]);
}

// Pack Wcat[128 x 256] where Wcat[k][f] = f<128 ? W1[k][f] : W1[128+k][f-128]
// blob[((ks*8+nt)*64+L)*8+j]
__global__ void pack_cat(const float* __restrict__ W1, unsigned short* __restrict__ blob) {
    int idx = blockIdx.x * 256 + threadIdx.x;
    if (idx >= 32768) return;
    int j  = idx & 7;
    int L  = (idx >> 3) & 63;
    int nt = (idx >> 9) & 7;
    int ks = idx >> 12;
    int k = ks * 16 + (L >> 5) * 8 + j;
    int f = nt * 32 + (L & 31);
    float v = (f < H) ? W1[k * H + f] : W1[(H + k) * H + (f - H)];
    blob[idx] = f2b(v);
}

__global__ void embed_kernel(const int* __restrict__ z, const float* __restrict__ emb,
                             unsigned short* __restrict__ hb, int n) {
    int idx = blockIdx.x * blockDim.x + threadIdx.x;
    if (idx >= n * H) return;
    int i = idx >> 7, j = idx & 127;
    hb[idx] = f2b(emb[z[i] * H + j]);
}

// ---------------- CSR build (counting sort by destination row) ----------------
__global__ void hist_kernel(const int* __restrict__ row, int* __restrict__ cnt, int nE) {
    int i = blockIdx.x * blockDim.x + threadIdx.x;
    if (i < nE) atomicAdd(&cnt[row[i]], 1);
}

__global__ __launch_bounds__(1024) void scan_kernel(const int* __restrict__ cnt,
                                                    int* __restrict__ rptr,
                                                    int* __restrict__ cur, int nN) {
    __shared__ int wsum[17];
    __shared__ int s_carry;
    int t = threadIdx.x;
    if (t == 0) s_carry = 0;
    __syncthreads();
    for (int base = 0; base < nN; base += 1024) {
        int i = base + t;
        int v = (i < nN) ? cnt[i] : 0;
        int x = v;
        #pragma unroll
        for (int off = 1; off < 64; off <<= 1) {
            int y = __shfl_up(x, off);
            if ((t & 63) >= off) x += y;
        }
        if ((t & 63) == 63) wsum[t >> 6] = x;
        __syncthreads();
        if (t == 0) {
            int s = 0;
            #pragma unroll
            for (int w = 0; w < 16; ++w) { int tmp = wsum[w]; wsum[w] = s; s += tmp; }
            wsum[16] = s;
        }
        __syncthreads();
        int cin = s_carry;
        int excl = cin + wsum[t >> 6] + (x - v);
        if (i < nN) { rptr[i] = excl; cur[i] = excl; }
        __syncthreads();
        if (t == 0) s_carry = cin + wsum[16];
        __syncthreads();
    }
    if (t == 0) rptr[nN] = s_carry;
}

__global__ void scatter_kernel(const int* __restrict__ row, const int* __restrict__ col,
                               const float* __restrict__ pos,
                               int* __restrict__ cur,
                               int* __restrict__ rowsS, int* __restrict__ colsS,
                               float* __restrict__ d2S, int nE) {
    int e = blockIdx.x * blockDim.x + threadIdx.x;
    if (e >= nE) return;
    int r = row[e], c = col[e];
    int p = atomicAdd(&cur[r], 1);
    rowsS[p] = r;
    colsS[p] = c;
    float dx = pos[r * 3 + 0] - pos[c * 3 + 0];
    float dy = pos[r * 3 + 1] - pos[c * 3 + 1];
    float dz = pos[r * 3 + 2] - pos[c * 3 + 2];
    d2S[p] = dx * dx + dy * dy + dz * dz;
}

// ---------------- per-node projection: P[n] = [h.W1a + b1 | h.W1b] ----------
// One GEMM [nN,128] @ [128,256], bf16 out. 32 nodes/block, 4 waves = 4 N-chunks.
__global__ __launch_bounds__(256) void proj_kernel(
    const unsigned short* __restrict__ hb,
    const unsigned short* __restrict__ pcat, const float* __restrict__ b1,
    unsigned short* __restrict__ P, int nN)
{
    const int t = threadIdx.x;
    const int wv = t >> 6, lane = t & 63;
    const int lm = lane & 31, lh = lane >> 5;
    const int i0 = blockIdx.x * 32;
    const int node = min(i0 + lm, nN - 1);
    const unsigned short* ap = hb + (size_t)node * H + lh * 8;
    const int n0 = wv * 64 + lm;

    floatx16 c0 = {}, c1 = {};
    #pragma unroll
    for (int ks = 0; ks < 8; ++ks) {
        frag_u a, fb0, fb1;
        a.u   = *(const ushort8*)(ap + ks * 16);
        fb0.u = *(const ushort8*)(pcat + (size_t)((ks * 8 + wv * 2 + 0) * 64 + lane) * 8);
        fb1.u = *(const ushort8*)(pcat + (size_t)((ks * 8 + wv * 2 + 1) * 64 + lane) * 8);
        c0 = __builtin_amdgcn_mfma_f32_32x32x16_bf16(a.b, fb0.b, c0, 0, 0, 0);
        c1 = __builtin_amdgcn_mfma_f32_32x32x16_bf16(a.b, fb1.b, c1, 0, 0, 0);
    }
    const float bias0 = (n0 < H)      ? b1[n0]      : 0.f;
    const float bias1 = (n0 + 32 < H) ? b1[n0 + 32] : 0.f;
    #pragma unroll
    for (int r = 0; r < 16; ++r) {
        int m = (r & 3) + 8 * (r >> 2) + 4 * lh;
        int nd = i0 + m;
        if (nd < nN) {
            P[(size_t)nd * 256 + n0]      = f2b(c0[r] + bias0);
            P[(size_t)nd * 256 + n0 + 32] = f2b(c1[r] + bias1);
        }
    }
}

// ---------------- edge MLP: GEMM1 factored out; t1 built in registers -------
// t1[k] = silu(Pa[row][k] + Pb[col][k] + d2*w1last[k]) -> A-frag for GEMM2.
// No LDS, no barriers. Epilogue: run-compaction + fp32 atomics (as before).
__global__ __launch_bounds__(256) void edge_p(
    const unsigned short* __restrict__ P,
    const int* __restrict__ rowsS, const int* __restrict__ colsS,
    const float* __restrict__ d2S,
    const float* __restrict__ w1last,
    const unsigned short* __restrict__ pb2, const float* __restrict__ b2v,
    float* __restrict__ agg, int nE)
{
    const int t = threadIdx.x;
    const int wv = t >> 6, lane = t & 63;
    const int wm = wv & 1, wn = wv >> 1;
    const int lm = lane & 31, lh = lane >> 5;
    const int n0 = wn * 64 + lm;
    const int p0 = blockIdx.x * ET;

    const int p = p0 + wm * 32 + lm;
    const bool valid = p < nE;
    const int pc = valid ? p : (nE - 1);
    const int nrow = rowsS[pc];
    const int ncol = colsS[pc];
    const float dd = d2S[pc];
    const int ptag = valid ? nrow : -1;

    const unsigned short* pap = P + (size_t)nrow * 256 + lh * 8;        // Pa
    const unsigned short* pbp = P + (size_t)ncol * 256 + 128 + lh * 8;  // Pb
    const float* wlp = w1last + lh * 8;

    const float bias20 = b2v[n0], bias21 = b2v[n0 + 32];

    // GEMM2 K-loop with in-register t1 construction
    floatx16 c0 = {}, c1 = {};
    #pragma unroll
    for (int ks = 0; ks < 8; ++ks) {
        frag_u pa, pb, a, fb0, fb1;
        pa.u  = *(const ushort8*)(pap + ks * 16);
        pb.u  = *(const ushort8*)(pbp + ks * 16);
        fb0.u = *(const ushort8*)(pb2 + (size_t)((ks * 4 + wn * 2 + 0) * 64 + lane) * 8);
        fb1.u = *(const ushort8*)(pb2 + (size_t)((ks * 4 + wn * 2 + 1) * 64 + lane) * 8);
        float4 wl0 = *(const float4*)(wlp + ks * 16);
        float4 wl1 = *(const float4*)(wlp + ks * 16 + 4);
        float wls[8] = {wl0.x, wl0.y, wl0.z, wl0.w, wl1.x, wl1.y, wl1.z, wl1.w};
        #pragma unroll
        for (int j = 0; j < 8; ++j) {
            float v = b2f_bits(pa.u[j]) + b2f_bits(pb.u[j]) + dd * wls[j];
            a.u[j] = f2b(silu(v));
        }
        c0 = __builtin_amdgcn_mfma_f32_32x32x16_bf16(a.b, fb0.b, c0, 0, 0, 0);
        c1 = __builtin_amdgcn_mfma_f32_32x32x16_bf16(a.b, fb1.b, c1, 0, 0, 0);
    }

    // epilogue: silu + register run-compaction (tags via shfl)
    #pragma unroll
    for (int g = 0; g < 4; ++g) {
        const int mi0 = 4 * lh + 8 * g;
        int prow = __shfl(ptag, mi0);
        float s0 = silu(c0[g * 4] + bias20);
        float s1 = silu(c1[g * 4] + bias21);
        #pragma unroll
        for (int k = 1; k < 4; ++k) {
            int rw = __shfl(ptag, mi0 + k);
            float u0 = silu(c0[g * 4 + k] + bias20);
            float u1 = silu(c1[g * 4 + k] + bias21);
            if (rw == prow) {
                s0 += u0; s1 += u1;
            } else {
                if (prow >= 0) {
                    atomicAdd(&agg[(size_t)prow * H + n0],      s0);
                    atomicAdd(&agg[(size_t)prow * H + n0 + 32], s1);
                }
                prow = rw; s0 = u0; s1 = u1;
            }
        }
        if (prow >= 0) {
            atomicAdd(&agg[(size_t)prow * H + n0],      s0);
            atomicAdd(&agg[(size_t)prow * H + n0 + 32], s1);
        }
    }
}

// ---------------- node MLP via MFMA (block-staged, proven) ----------------
__global__ __launch_bounds__(256) void node_mfma(
    const unsigned short* __restrict__ hb,
    const float* __restrict__ aggf,
    const unsigned short* __restrict__ pn1, const float* __restrict__ b1,
    const unsigned short* __restrict__ pn2, const float* __restrict__ b2,
    float* __restrict__ hnew, int nN)
{
    __shared__ __align__(16) unsigned short sA[ET * 264];

    const int t = threadIdx.x;
    const int i0 = blockIdx.x * ET;

    #pragma unroll
    for (int c = t; c < ET * 32; c += 256) {
        int e = c >> 5;
        int node = i0 + e; if (node >= nN) node = nN - 1;
        int f0 = (c & 31) * 8;
        ushort8 v;
        if (f0 < H) {
            v = *(const ushort8*)(hb + (size_t)node * H + f0);
        } else {
            const float* src = aggf + (size_t)node * H + (f0 - H);
            #pragma unroll
            for (int j = 0; j < 8; ++j) v[j] = f2b(src[j]);
        }
        *(ushort8*)(sA + e * 264 + (c & 31) * 8) = v;
    }
    __syncthreads();

    const int lane = t & 63;
    const int wv = t >> 6;
    const int wm = wv & 1, wn = wv >> 1;
    const int lm = lane & 31, lh = lane >> 5;
    const int n0 = wn * 64 + lm;

    floatx16 acc0 = {}, acc1 = {};
    const unsigned short* A0 = sA + (wm * 32 + lm) * 264 + lh * 8;
    #pragma unroll
    for (int ks = 0; ks < 16; ++ks) {
        frag_u a, fb0, fb1;
        a.u   = *(const ushort8*)(A0 + ks * 16);
        fb0.u = *(const ushort8*)(pn1 + (size_t)((ks * 4 + wn * 2 + 0) * 64 + lane) * 8);
        fb1.u = *(const ushort8*)(pn1 + (size_t)((ks * 4 + wn * 2 + 1) * 64 + lane) * 8);
        acc0 = __builtin_amdgcn_mfma_f32_32x32x16_bf16(a.b, fb0.b, acc0, 0, 0, 0);
        acc1 = __builtin_amdgcn_mfma_f32_32x32x16_bf16(a.b, fb1.b, acc1, 0, 0, 0);
    }
    __syncthreads();   // sA reads done before sT (aliased) written

    unsigned short* sT = sA;
    {
        float bias0 = b1[n0], bias1 = b1[n0 + 32];
        #pragma unroll
        for (int r = 0; r < 16; ++r) {
            int m = wm * 32 + (r & 3) + 8 * (r >> 2) + 4 * lh;
            sT[m * 136 + n0]      = f2b(silu(acc0[r] + bias0));
            sT[m * 136 + n0 + 32] = f2b(silu(acc1[r] + bias1));
        }
    }
    __syncthreads();

    floatx16 c0 = {}, c1 = {};
    const unsigned short* A2 = sT + (wm * 32 + lm) * 136 + lh * 8;
    #pragma unroll
    for (int ks = 0; ks < 8; ++ks) {
        frag_u a, fb0, fb1;
        a.u   = *(const ushort8*)(A2 + ks * 16);
        fb0.u = *(const ushort8*)(pn2 + (size_t)((ks * 4 + wn * 2 + 0) * 64 + lane) * 8);
        fb1.u = *(const ushort8*)(pn2 + (size_t)((ks * 4 + wn * 2 + 1) * 64 + lane) * 8);
        c0 = __builtin_amdgcn_mfma_f32_32x32x16_bf16(a.b, fb0.b, c0, 0, 0, 0);
        c1 = __builtin_amdgcn_mfma_f32_32x32x16_bf16(a.b, fb1.b, c1, 0, 0, 0);
    }
    {
        float bias0 = b2[n0], bias1 = b2[n0 + 32];
        #pragma unroll
        for (int r = 0; r < 16; ++r) {
            int m = wm * 32 + (r & 3) + 8 * (r >> 2) + 4 * lh;
            int node = i0 + m;
            if (node < nN) {
                float* dst = hnew + (size_t)node * H;
                dst[n0]      = c0[r] + bias0;
                dst[n0 + 32] = c1[r] + bias1;
            }
        }
    }
}

// residual + layernorm on bf16 residual stream
__global__ __launch_bounds__(256) void ln_kernel(
    unsigned short* __restrict__ hb,
    const float* __restrict__ hnew,
    const float* __restrict__ G, const float* __restrict__ B, int nN)
{
    __shared__ float rs[4], rq[4];
    int t = threadIdx.x;
    int local = t >> 7, j = t & 127;
    int i = blockIdx.x * 2 + local;
    float v = 0.f;
    if (i < nN) v = b2f_bits(hb[(size_t)i * H + j]) + hnew[(size_t)i * H + j];
    float s = v, q = v * v;
    #pragma unroll
    for (int off = 32; off > 0; off >>= 1) {
        s += __shfl_down(s, off);
        q += __shfl_down(q, off);
    }
    int w = t >> 6;
    if ((t & 63) == 0) { rs[w] = s; rq[w] = q; }
    __syncthreads();
    int w0 = local * 2;
    float S = rs[w0] + rs[w0 + 1], Q = rq[w0] + rq[w0 + 1];
    float mu = S * (1.f / H);
    float var = Q * (1.f / H) - mu * mu;
    float y = (v - mu) * rsqrtf(var + LN_EPS) * G[j] + B[j];
    if (i < nN) hb[(size_t)i * H + j] = f2b(y);
}

__global__ void cast_kernel(const unsigned short* __restrict__ hb, void* __restrict__ out,
                            int n, const int* __restrict__ flag) {
    int idx = blockIdx.x * blockDim.x + threadIdx.x;
    if (idx >= n) return;
    if (*flag) ((float*)out)[idx] = b2f_bits(hb[idx]);
    else       ((unsigned short*)out)[idx] = hb[idx];
}

extern "C" void kernel_launch(void* const* d_in, const int* in_sizes, int n_in,
                              void* d_out, int out_size, void* d_ws, size_t ws_size,
                              hipStream_t stream)
{
    const int* z  = (const int*)d_in[0];
    const int* ei = (const int*)d_in[2];

    const int nN = in_sizes[0];
    const int nE = in_sizes[2] / 2;
    const int* row = ei;
    const int* col = ei + nE;

    // ---- workspace layout (~79 MB, within proven budget) ----
    float* ws   = (float*)d_ws;
    int*   flag = (int*)ws;
    unsigned short* hb = (unsigned short*)(ws + 64);                  // bf16 residual stream
    float* agg  = (float*)(hb + (size_t)nN * H);                      // fp32 agg / hnew
    unsigned short* P = (unsigned short*)(agg + (size_t)nN * H);      // bf16 [nN][256]
    float* conv = (float*)(P + (size_t)nN * 256);

    const int n_pos = in_sizes[1];
    const int n_emb = in_sizes[3];
    const int n_ew1 = in_sizes[4], n_eb1 = in_sizes[5];
    const int n_ew2 = in_sizes[6], n_eb2 = in_sizes[7];
    const int n_nw1 = in_sizes[8], n_nb1 = in_sizes[9];
    const int n_nw2 = in_sizes[10], n_nb2 = in_sizes[11];
    const int n_lng = in_sizes[12], n_lnb = in_sizes[13];

    float* pos = conv;
    float* emb = pos + n_pos;
    float* ew1 = emb + n_emb;
    float* eb1 = ew1 + n_ew1;
    float* ew2 = eb1 + n_eb1;
    float* eb2 = ew2 + n_ew2;
    float* nw1 = eb2 + n_eb2;
    float* nb1 = nw1 + n_nw1;
    float* nw2 = nb1 + n_nb1;
    float* nb2 = nw2 + n_nw2;
    float* lng = nb2 + n_nb2;
    float* lnb = lng + n_lng;
    float* conv_end = lnb + n_lnb;

    unsigned short* pb2  = (unsigned short*)conv_end;   // 4 x 16384
    unsigned short* pn1  = pb2 + 4 * 16384;             // 4 x 32768
    unsigned short* pn2  = pn1 + 4 * 32768;             // 4 x 16384
    unsigned short* pcat = pn2 + 4 * 16384;             // 4 x 32768

    int* cnt   = (int*)(pcat + 4 * 32768);
    int* rptr  = cnt + nN;
    int* cur   = rptr + nN + 1;
    int* rowsS = cur + nN;
    int* colsS = rowsS + nE;
    float* d2S = (float*)(colsS + nE);

    detect_kernel<<<1, 64, 0, stream>>>((const unsigned short*)d_in[4], 4096, flag);

    struct { const void* src; float* dst; int n; } cv[12] = {
        {d_in[1],  pos, n_pos}, {d_in[3],  emb, n_emb},
        {d_in[4],  ew1, n_ew1}, {d_in[5],  eb1, n_eb1},
        {d_in[6],  ew2, n_ew2}, {d_in[7],  eb2, n_eb2},
        {d_in[8],  nw1, n_nw1}, {d_in[9],  nb1, n_nb1},
        {d_in[10], nw2, n_nw2}, {d_in[11], nb2, n_nb2},
        {d_in[12], lng, n_lng}, {d_in[13], lnb, n_lnb},
    };
    for (int i = 0; i < 12; ++i)
        conv_kernel<<<(cv[i].n + 255) / 256, 256, 0, stream>>>(cv[i].src, cv[i].dst, cv[i].n, flag);

    for (int l = 0; l < NLAYERS; ++l) {
        pack_cat<<<128, 256, 0, stream>>>(ew1 + (size_t)l * 257 * H, pcat + l * 32768);
        pack_kernel<<<64,  256, 0, stream>>>(ew2 + (size_t)l * H * H,   pb2 + l * 16384, 8);
        pack_kernel<<<128, 256, 0, stream>>>(nw1 + (size_t)l * 2 * H * H, pn1 + l * 32768, 16);
        pack_kernel<<<64,  256, 0, stream>>>(nw2 + (size_t)l * H * H,   pn2 + l * 16384, 8);
    }

    // CSR-order edges (counting sort by destination row)
    hipMemsetAsync(cnt, 0, (size_t)nN * sizeof(int), stream);
    hist_kernel<<<(nE + 255) / 256, 256, 0, stream>>>(row, cnt, nE);
    scan_kernel<<<1, 1024, 0, stream>>>(cnt, rptr, cur, nN);
    scatter_kernel<<<(nE + 255) / 256, 256, 0, stream>>>(row, col, pos, cur, rowsS, colsS, d2S, nE);

    embed_kernel<<<(nN * H + 255) / 256, 256, 0, stream>>>(z, emb, hb, nN);

    const int nTilesE = (nE + ET - 1) / ET;
    const int nTilesN = (nN + ET - 1) / ET;
    const int nTilesP = (nN + 31) / 32;
    for (int l = 0; l < NLAYERS; ++l) {
        proj_kernel<<<nTilesP, 256, 0, stream>>>(
            hb, pcat + l * 32768, eb1 + (size_t)l * H, P, nN);
        hipMemsetAsync(agg, 0, (size_t)nN * H * sizeof(float), stream);
        edge_p<<<nTilesE, 256, 0, stream>>>(
            P, rowsS, colsS, d2S,
            ew1 + (size_t)l * 257 * H + 256 * H,
            pb2 + l * 16384, eb2 + (size_t)l * H,
            agg, nE);
        node_mfma<<<nTilesN, 256, 0, stream>>>(
            hb, agg,
            pn1 + l * 32768, nb1 + (size_t)l * H,
            pn2 + l * 16384, nb2 + (size_t)l * H,
            agg /* hnew, in place */, nN);
        ln_kernel<<<(nN + 1) / 2, 256, 0, stream>>>(
            hb, agg, lng + (size_t)l * H, lnb + (size_t)l * H, nN);
    }
    cast_kernel<<<(nN * H + 255) / 256, 256, 0, stream>>>(hb, d_out, nN * H, flag);
}